// Round 9
// baseline (81.435 us; speedup 1.0000x reference)
//
#include <hip/hip_runtime.h>

typedef float f32x4 __attribute__((ext_vector_type(4)));
typedef short s16x8 __attribute__((ext_vector_type(8)));

#define CB_PLANE 2704   // 52*52
#define CB_ROW 52

// software f32->bf16 RNE (proven R3-R8)
__device__ __forceinline__ ushort f2bf(float f) {
  unsigned u = __float_as_uint(f);
  unsigned r = (u + 0x7fffu + ((u >> 16) & 1u)) >> 16;
  return (ushort)r;
}
__device__ __forceinline__ uint pk2(float a, float b) {
  return (uint)f2bf(a) | ((uint)f2bf(b) << 16);
}

// ---- conv1 epilogue: bias+relu, scatter into conv2 im2col (proven R8) ----
__device__ __forceinline__ void epi1(ushort* A2, f32x4 acc, int mt, int r16,
                                     int g, float b1v) {
#pragma unroll
  for (int rr = 0; rr < 4; ++rr) {
    int m = mt * 16 + g * 4 + rr;
    int oy = m / 12, ox = m - 12 * oy;
    if (oy < 11 && ox < 11) {
      float v = fmaxf(acc[rr] + b1v, 0.f);
      int py = (oy + 1) >> 2, k2y = (oy + 1) & 3;
      int px = (ox + 1) >> 2, k2x = (ox + 1) & 3;
      A2[(py * 3 + px) * 264 + r16 * 16 + k2y * 4 + k2x] = f2bf(v);
    }
  }
}

// ================= Kernel A: conv1 + conv2, one cell per block =============
__global__ __launch_bounds__(256, 6)
void conv_kernel(const float* __restrict__ x,
                 const float* __restrict__ w1, const float* __restrict__ b1,
                 const float* __restrict__ w2, const float* __restrict__ b2,
                 ushort* __restrict__ h2g)
{
  __shared__ __align__(16) ushort cb[3 * CB_PLANE];  // 16224 B padded bf16 cell
  __shared__ __align__(16) ushort A2[16 * 264];      // 8448 B im2col for conv2

  const int t = threadIdx.x;
  const int w = t >> 6;
  const int r16 = t & 15;
  const int g = (t & 63) >> 4;
  const int cell = blockIdx.x;

  // ---- issue staging loads first (deep MLP): 1728 float4 of this cell ----
  const int b = cell >> 6, gg = cell & 63;
  const float4* x4 = (const float4*)x;
  const int base4 = b * 110592 + (gg >> 3) * 4608 + (gg & 7) * 12;
  float4 v[7];
  int eoff[7];
#pragma unroll
  for (int i = 0; i < 7; ++i) {
    int q = i * 256 + t;
    bool valid = (i < 6) || (t < 192);          // 1728 = 6*256 + 192
    int qq = valid ? q : 0;
    int c = qq / 576; int r2 = qq - c * 576;
    int y = r2 / 12;  int quad = r2 - y * 12;
    eoff[i] = valid ? (c * CB_PLANE + (y + 2) * CB_ROW + 2 + quad * 4) : -1;
    if (valid) v[i] = x4[base4 + c * 36864 + y * 96 + quad];
  }

  // ---- zero cb borders + A2 (overlaps loads in flight) ----
  {
    uint4 z = make_uint4(0u, 0u, 0u, 0u);
    uint4* p1 = (uint4*)cb;                      // 2028 uint4
    for (int i = t; i < 2028; i += 256) p1[i] = z;
    uint4* p2 = (uint4*)A2;                      // 528 uint4
    for (int i = t; i < 528; i += 256) p2[i] = z;
  }

  // ---- conv1 B-fragments: w1[oc=r16][k=32s+8g..+7] fp32->bf16 (proven R8) ----
  s16x8 b1f[6];
#pragma unroll
  for (int s = 0; s < 6; ++s) {
    const float2* wp = (const float2*)(w1 + r16 * 192 + s * 32 + g * 8);
    float2 q0 = wp[0], q1 = wp[1], q2 = wp[2], q3 = wp[3];
    s16x8 bf;
    ((uint*)&bf)[0] = pk2(q0.x, q0.y);
    ((uint*)&bf)[1] = pk2(q1.x, q1.y);
    ((uint*)&bf)[2] = pk2(q2.x, q2.y);
    ((uint*)&bf)[3] = pk2(q3.x, q3.y);
    b1f[s] = bf;
  }
  const float b1v = b1[r16];

  __syncthreads();                               // zeros visible

  // ---- write staged pixels (convert once per pixel) ----
#pragma unroll
  for (int i = 0; i < 7; ++i)
    if (eoff[i] >= 0) {
      float4 q = v[i]; int e = eoff[i];
      *(uint*)&cb[e]     = pk2(q.x, q.y);
      *(uint*)&cb[e + 2] = pk2(q.z, q.w);
    }
  __syncthreads();

  // ---- conv1 MFMA: M=144 = 9 m-tiles; wave w owns {w, w+4}, wave 2 also 8 ----
  const int mt0 = w, mt1 = w + 4;
  int m0 = mt0 * 16 + r16, m1 = mt1 * 16 + r16, m2_ = 128 + r16;
  const int rA0 = (m0 / 12) * (4 * CB_ROW) + 4 * (m0 % 12);
  const int rA1 = (m1 / 12) * (4 * CB_ROW) + 4 * (m1 % 12);
  const int rA2 = (m2_ / 12) * (4 * CB_ROW) + 4 * (m2_ % 12);

  f32x4 a0 = (f32x4){0.f, 0.f, 0.f, 0.f};
  f32x4 a1 = (f32x4){0.f, 0.f, 0.f, 0.f};
  f32x4 a2 = (f32x4){0.f, 0.f, 0.f, 0.f};
#pragma unroll
  for (int s = 0; s < 6; ++s) {
    int sbase = (s >> 1) * CB_PLANE + ((s & 1) * 4 + g) * CB_ROW;
    s16x8 a;
    ((uint2*)&a)[0] = *(const uint2*)&cb[sbase + rA0];
    ((uint2*)&a)[1] = *(const uint2*)&cb[sbase + rA0 + 4];
    a0 = __builtin_amdgcn_mfma_f32_16x16x32_bf16(a, b1f[s], a0, 0, 0, 0);
    ((uint2*)&a)[0] = *(const uint2*)&cb[sbase + rA1];
    ((uint2*)&a)[1] = *(const uint2*)&cb[sbase + rA1 + 4];
    a1 = __builtin_amdgcn_mfma_f32_16x16x32_bf16(a, b1f[s], a1, 0, 0, 0);
    if (w == 2) {
      ((uint2*)&a)[0] = *(const uint2*)&cb[sbase + rA2];
      ((uint2*)&a)[1] = *(const uint2*)&cb[sbase + rA2 + 4];
      a2 = __builtin_amdgcn_mfma_f32_16x16x32_bf16(a, b1f[s], a2, 0, 0, 0);
    }
  }
  epi1(A2, a0, mt0, r16, g, b1v);
  epi1(A2, a1, mt1, r16, g, b1v);
  if (w == 2) epi1(A2, a2, 8, r16, g, b1v);

  __syncthreads();

  // ---- conv2: M=9(pad16), N=32 -> waves 0,1; K=256 (proven R8) ----
  if (w < 2) {
    const float b2v = b2[w * 16 + r16];
    f32x4 c2acc = (f32x4){0.f, 0.f, 0.f, 0.f};
    const float2* w2p = (const float2*)(w2 + (w * 16 + r16) * 256 + g * 8);
#pragma unroll
    for (int s2 = 0; s2 < 8; ++s2) {
      uint4 av = *(const uint4*)&A2[r16 * 264 + s2 * 32 + g * 8];
      float2 q0 = w2p[s2 * 16 + 0], q1 = w2p[s2 * 16 + 1],
             q2 = w2p[s2 * 16 + 2], q3 = w2p[s2 * 16 + 3];
      s16x8 bf;
      ((uint*)&bf)[0] = pk2(q0.x, q0.y);
      ((uint*)&bf)[1] = pk2(q1.x, q1.y);
      ((uint*)&bf)[2] = pk2(q2.x, q2.y);
      ((uint*)&bf)[3] = pk2(q3.x, q3.y);
      c2acc = __builtin_amdgcn_mfma_f32_16x16x32_bf16(*(s16x8*)&av, bf, c2acc, 0, 0, 0);
    }
#pragma unroll
    for (int rr = 0; rr < 4; ++rr) {
      int p2 = g * 4 + rr;
      if (p2 < 9) {
        float vv = fmaxf(c2acc[rr] + b2v, 0.f);
        h2g[cell * 288 + (w * 16 + r16) * 9 + p2] = f2bf(vv);
      }
    }
  }
}

// ============ Kernel B: fc1(MFMA) + fc2 + softmax (unchanged from R8) ======
__global__ __launch_bounds__(256, 4)
void fc_kernel(const float* __restrict__ fw1, const float* __restrict__ fb1,
               const float* __restrict__ fw2, const float* __restrict__ fb2,
               const ushort* __restrict__ h2g, float* __restrict__ out)
{
  __shared__ __align__(16) ushort h2s[16 * 296];
  __shared__ __align__(16) float h3s[16 * 260];
  __shared__ float ls[16][4];

  const int t = threadIdx.x;
  const int w = t >> 6;
  const int r16 = t & 15;
  const int g = (t & 63) >> 4;
  const int c0 = blockIdx.x * 16;

  const uint* src = (const uint*)(h2g + c0 * 288);
  for (int j = t; j < 2304; j += 256) {
    int r = j / 144, ci = j - r * 144;
    *(uint*)&h2s[r * 296 + 2 * ci] = src[j];
  }
  __syncthreads();

  s16x8 af[9];
#pragma unroll
  for (int s = 0; s < 9; ++s)
    af[s] = *(const s16x8*)&h2s[r16 * 296 + s * 32 + g * 8];

  f32x4 fa0 = (f32x4){0.f,0.f,0.f,0.f}, fa1 = fa0, fa2 = fa0, fa3 = fa0;
#pragma unroll
  for (int s = 0; s < 9; ++s) {
    const int ko = s * 32 + g * 8;
#pragma unroll
    for (int i = 0; i < 4; ++i) {
      const float2* p = (const float2*)(fw1 + ((w * 4 + i) * 16 + r16) * 288 + ko);
      float2 q0 = p[0], q1 = p[1], q2 = p[2], q3 = p[3];
      s16x8 bf;
      ((uint*)&bf)[0] = pk2(q0.x, q0.y);
      ((uint*)&bf)[1] = pk2(q1.x, q1.y);
      ((uint*)&bf)[2] = pk2(q2.x, q2.y);
      ((uint*)&bf)[3] = pk2(q3.x, q3.y);
      if (i == 0) fa0 = __builtin_amdgcn_mfma_f32_16x16x32_bf16(af[s], bf, fa0, 0, 0, 0);
      if (i == 1) fa1 = __builtin_amdgcn_mfma_f32_16x16x32_bf16(af[s], bf, fa1, 0, 0, 0);
      if (i == 2) fa2 = __builtin_amdgcn_mfma_f32_16x16x32_bf16(af[s], bf, fa2, 0, 0, 0);
      if (i == 3) fa3 = __builtin_amdgcn_mfma_f32_16x16x32_bf16(af[s], bf, fa3, 0, 0, 0);
    }
  }
#pragma unroll
  for (int i = 0; i < 4; ++i) {
    f32x4 fa = (i == 0) ? fa0 : (i == 1) ? fa1 : (i == 2) ? fa2 : fa3;
    int n = (w * 4 + i) * 16 + r16;
    float fb = fb1[n];
#pragma unroll
    for (int rr = 0; rr < 4; ++rr)
      h3s[(g * 4 + rr) * 260 + n] = fmaxf(fa[rr] + fb, 0.f);
  }
  __syncthreads();

  {
    int u = t >> 2, sub = t & 3;
    int cl = u >> 2, j = u & 3;
    const float4* hp = (const float4*)&h3s[cl * 260];
    const float4* wp = (const float4*)(fw2 + j * 256);
    float p = 0.f;
#pragma unroll
    for (int i = 0; i < 16; ++i) {
      int k4 = sub + 4 * i;
      float4 a = hp[k4], bb = wp[k4];
      p = fmaf(a.x, bb.x, p); p = fmaf(a.y, bb.y, p);
      p = fmaf(a.z, bb.z, p); p = fmaf(a.w, bb.w, p);
    }
    p += __shfl_xor(p, 1);
    p += __shfl_xor(p, 2);
    if (sub == 0) ls[cl][j] = p + fb2[j];
  }
  __syncthreads();

  if (t < 16) {
    float l0 = ls[t][0], l1 = ls[t][1], l2 = ls[t][2], l3 = ls[t][3];
    float m = fmaxf(fmaxf(l0, l1), fmaxf(l2, l3));
    float e0 = __expf(l0 - m), e1 = __expf(l1 - m),
          e2 = __expf(l2 - m), e3 = __expf(l3 - m);
    float inv = 1.f / (e0 + e1 + e2 + e3);
    int n = c0 + t;
    out[n] = e0 * inv;
    out[4096 + n] = e1 * inv;
    out[8192 + n] = e2 * inv;
  }
}

extern "C" void kernel_launch(void* const* d_in, const int* in_sizes, int n_in,
                              void* d_out, int out_size, void* d_ws, size_t ws_size,
                              hipStream_t stream) {
  const float* x   = (const float*)d_in[0];
  const float* w1  = (const float*)d_in[1];
  const float* b1  = (const float*)d_in[2];
  const float* w2  = (const float*)d_in[3];
  const float* b2  = (const float*)d_in[4];
  const float* fw1 = (const float*)d_in[5];
  const float* fb1 = (const float*)d_in[6];
  const float* fw2 = (const float*)d_in[7];
  const float* fb2 = (const float*)d_in[8];
  float* out = (float*)d_out;
  ushort* h2g = (ushort*)d_ws;   // 4096*288*2 = 2,359,296 B conv2 output (bf16)

  hipLaunchKernelGGL(conv_kernel, dim3(4096), dim3(256), 0, stream,
                     x, w1, b1, w2, b2, h2g);
  hipLaunchKernelGGL(fc_kernel, dim3(256), dim3(256), 0, stream,
                     fw1, fb1, fw2, fb2, h2g, out);
}

// Round 10
// 64.748 us; speedup vs baseline: 1.2577x; 1.2577x over previous
//
#include <hip/hip_runtime.h>

typedef float f32x4 __attribute__((ext_vector_type(4)));
typedef short s16x8 __attribute__((ext_vector_type(8)));

#define CB_PLANE 2704   // 52*52 ushorts
#define CB_ROW 52

// software f32->bf16 RNE (proven R3-R9)
__device__ __forceinline__ ushort f2bf(float f) {
  unsigned u = __float_as_uint(f);
  unsigned r = (u + 0x7fffu + ((u >> 16) & 1u)) >> 16;
  return (ushort)r;
}
__device__ __forceinline__ uint pk2(float a, float b) {
  return (uint)f2bf(a) | ((uint)f2bf(b) << 16);
}

// ---- conv1 epilogue: bias+relu, scatter into conv2 im2col (proven R8) ----
__device__ __forceinline__ void epi1(ushort* A2, f32x4 acc, int mt, int r16,
                                     int g, float b1v) {
#pragma unroll
  for (int rr = 0; rr < 4; ++rr) {
    int m = mt * 16 + g * 4 + rr;
    int oy = m / 12, ox = m - 12 * oy;
    if (oy < 11 && ox < 11) {
      float v = fmaxf(acc[rr] + b1v, 0.f);
      int py = (oy + 1) >> 2, k2y = (oy + 1) & 3;
      int px = (ox + 1) >> 2, k2x = (ox + 1) & 3;
      A2[(py * 3 + px) * 264 + r16 * 16 + k2y * 4 + k2x] = f2bf(v);
    }
  }
}

// ================= Kernel A: conv1 + conv2, one cell per block =============
__global__ __launch_bounds__(256, 6)
void conv_kernel(const float* __restrict__ x,
                 const float* __restrict__ w1, const float* __restrict__ b1,
                 const float* __restrict__ w2, const float* __restrict__ b2,
                 ushort* __restrict__ h2g)
{
  __shared__ __align__(16) ushort cb[3 * CB_PLANE];  // 16224 B padded bf16 cell
  __shared__ __align__(16) ushort A2[16 * 264];      // 8448 B im2col for conv2

  const int t = threadIdx.x;
  const int w = t >> 6;
  const int r16 = t & 15;
  const int g = (t & 63) >> 4;
  const int cell = blockIdx.x;

  const int b = cell >> 6, gg = cell & 63;
  const float4* x4 = (const float4*)x;
  const int base4 = b * 110592 + (gg >> 3) * 4608 + (gg & 7) * 12;

  // ---- issue the cell's 1728 coalesced float4 loads ----
  float4 v[7];
  int e[7];
#pragma unroll
  for (int i = 0; i < 7; ++i) {
    int q = i * 256 + t;
    if (i < 6 || t < 192) {                       // 1728 = 6*256 + 192
      int c = q / 576; int r2 = q - c * 576;
      int y = r2 / 12;  int quad = r2 - y * 12;
      v[i] = x4[base4 + c * 36864 + y * 96 + quad];
      e[i] = c * CB_PLANE + (y + 2) * CB_ROW + 2 + quad * 4;
    }
  }

  // ---- border-only zero of cb (disjoint from staged writes -> NO barrier)
  // per plane (uint idx): rows0-1 = [0,52), rows50-51 = [1300,1352),
  // cols0-1 of y=2..49 = y*26, cols50-51 = y*26+25.  600 uints total.
  for (int i = t; i < 600; i += 256) {
    int pl = i / 200, r = i - pl * 200;
    int off;
    if (r < 52)        off = r;
    else if (r < 104)  off = 1300 + (r - 52);
    else if (r < 152)  off = (2 + (r - 104)) * 26;
    else               off = (2 + (r - 152)) * 26 + 25;
    ((uint*)cb)[pl * 1352 + off] = 0u;
  }
  // A2 zero (epi1 writes come after the staging barrier -> ordered)
  {
    uint4 z = make_uint4(0u, 0u, 0u, 0u);
    uint4* p2 = (uint4*)A2;
    for (int i = t; i < 528; i += 256) p2[i] = z;
  }

  // ---- write staged pixels as loads land (convert once per pixel) ----
#pragma unroll
  for (int i = 0; i < 7; ++i)
    if (i < 6 || t < 192) {
      float4 q = v[i]; int ee = e[i];
      *(uint*)&cb[ee]     = pk2(q.x, q.y);
      *(uint*)&cb[ee + 2] = pk2(q.z, q.w);
    }

  // ---- conv1 B-fragments: w1[oc=r16][k=32s+8g..+7] fp32->bf16 ----
  s16x8 b1f[6];
#pragma unroll
  for (int s = 0; s < 6; ++s) {
    const float2* wp = (const float2*)(w1 + r16 * 192 + s * 32 + g * 8);
    float2 q0 = wp[0], q1 = wp[1], q2 = wp[2], q3 = wp[3];
    s16x8 bf;
    ((uint*)&bf)[0] = pk2(q0.x, q0.y);
    ((uint*)&bf)[1] = pk2(q1.x, q1.y);
    ((uint*)&bf)[2] = pk2(q2.x, q2.y);
    ((uint*)&bf)[3] = pk2(q3.x, q3.y);
    b1f[s] = bf;
  }
  const float b1v = b1[r16];

  __syncthreads();                               // staging + zeros complete

  // ---- conv1 MFMA: M=144 = 9 m-tiles; wave w owns {w, w+4}, wave 2 also 8 ----
  const int mt0 = w, mt1 = w + 4;
  int m0 = mt0 * 16 + r16, m1 = mt1 * 16 + r16, m2_ = 128 + r16;
  const int rA0 = (m0 / 12) * (4 * CB_ROW) + 4 * (m0 % 12);
  const int rA1 = (m1 / 12) * (4 * CB_ROW) + 4 * (m1 % 12);
  const int rA2 = (m2_ / 12) * (4 * CB_ROW) + 4 * (m2_ % 12);

  f32x4 a0 = (f32x4){0.f, 0.f, 0.f, 0.f};
  f32x4 a1 = (f32x4){0.f, 0.f, 0.f, 0.f};
  f32x4 a2 = (f32x4){0.f, 0.f, 0.f, 0.f};
#pragma unroll
  for (int s = 0; s < 6; ++s) {
    int sbase = (s >> 1) * CB_PLANE + ((s & 1) * 4 + g) * CB_ROW;
    s16x8 a;
    ((uint2*)&a)[0] = *(const uint2*)&cb[sbase + rA0];
    ((uint2*)&a)[1] = *(const uint2*)&cb[sbase + rA0 + 4];
    a0 = __builtin_amdgcn_mfma_f32_16x16x32_bf16(a, b1f[s], a0, 0, 0, 0);
    ((uint2*)&a)[0] = *(const uint2*)&cb[sbase + rA1];
    ((uint2*)&a)[1] = *(const uint2*)&cb[sbase + rA1 + 4];
    a1 = __builtin_amdgcn_mfma_f32_16x16x32_bf16(a, b1f[s], a1, 0, 0, 0);
    if (w == 2) {
      ((uint2*)&a)[0] = *(const uint2*)&cb[sbase + rA2];
      ((uint2*)&a)[1] = *(const uint2*)&cb[sbase + rA2 + 4];
      a2 = __builtin_amdgcn_mfma_f32_16x16x32_bf16(a, b1f[s], a2, 0, 0, 0);
    }
  }
  epi1(A2, a0, mt0, r16, g, b1v);
  epi1(A2, a1, mt1, r16, g, b1v);
  if (w == 2) epi1(A2, a2, 8, r16, g, b1v);

  __syncthreads();

  // ---- conv2: M=9(pad16), N=32 -> waves 0,1; K=256 (proven R8) ----
  if (w < 2) {
    const float b2v = b2[w * 16 + r16];
    f32x4 c2acc = (f32x4){0.f, 0.f, 0.f, 0.f};
    const float2* w2p = (const float2*)(w2 + (w * 16 + r16) * 256 + g * 8);
#pragma unroll
    for (int s2 = 0; s2 < 8; ++s2) {
      uint4 av = *(const uint4*)&A2[r16 * 264 + s2 * 32 + g * 8];
      float2 q0 = w2p[s2 * 16 + 0], q1 = w2p[s2 * 16 + 1],
             q2 = w2p[s2 * 16 + 2], q3 = w2p[s2 * 16 + 3];
      s16x8 bf;
      ((uint*)&bf)[0] = pk2(q0.x, q0.y);
      ((uint*)&bf)[1] = pk2(q1.x, q1.y);
      ((uint*)&bf)[2] = pk2(q2.x, q2.y);
      ((uint*)&bf)[3] = pk2(q3.x, q3.y);
      c2acc = __builtin_amdgcn_mfma_f32_16x16x32_bf16(*(s16x8*)&av, bf, c2acc, 0, 0, 0);
    }
#pragma unroll
    for (int rr = 0; rr < 4; ++rr) {
      int p2 = g * 4 + rr;
      if (p2 < 9) {
        float vv = fmaxf(c2acc[rr] + b2v, 0.f);
        h2g[cell * 288 + (w * 16 + r16) * 9 + p2] = f2bf(vv);
      }
    }
  }
}

// ============ Kernel B: fc1(MFMA) + fc2 + softmax (unchanged from R8) ======
__global__ __launch_bounds__(256, 4)
void fc_kernel(const float* __restrict__ fw1, const float* __restrict__ fb1,
               const float* __restrict__ fw2, const float* __restrict__ fb2,
               const ushort* __restrict__ h2g, float* __restrict__ out)
{
  __shared__ __align__(16) ushort h2s[16 * 296];
  __shared__ __align__(16) float h3s[16 * 260];
  __shared__ float ls[16][4];

  const int t = threadIdx.x;
  const int w = t >> 6;
  const int r16 = t & 15;
  const int g = (t & 63) >> 4;
  const int c0 = blockIdx.x * 16;

  const uint* src = (const uint*)(h2g + c0 * 288);
  for (int j = t; j < 2304; j += 256) {
    int r = j / 144, ci = j - r * 144;
    *(uint*)&h2s[r * 296 + 2 * ci] = src[j];
  }
  __syncthreads();

  s16x8 af[9];
#pragma unroll
  for (int s = 0; s < 9; ++s)
    af[s] = *(const s16x8*)&h2s[r16 * 296 + s * 32 + g * 8];

  f32x4 fa0 = (f32x4){0.f,0.f,0.f,0.f}, fa1 = fa0, fa2 = fa0, fa3 = fa0;
#pragma unroll
  for (int s = 0; s < 9; ++s) {
    const int ko = s * 32 + g * 8;
#pragma unroll
    for (int i = 0; i < 4; ++i) {
      const float2* p = (const float2*)(fw1 + ((w * 4 + i) * 16 + r16) * 288 + ko);
      float2 q0 = p[0], q1 = p[1], q2 = p[2], q3 = p[3];
      s16x8 bf;
      ((uint*)&bf)[0] = pk2(q0.x, q0.y);
      ((uint*)&bf)[1] = pk2(q1.x, q1.y);
      ((uint*)&bf)[2] = pk2(q2.x, q2.y);
      ((uint*)&bf)[3] = pk2(q3.x, q3.y);
      if (i == 0) fa0 = __builtin_amdgcn_mfma_f32_16x16x32_bf16(af[s], bf, fa0, 0, 0, 0);
      if (i == 1) fa1 = __builtin_amdgcn_mfma_f32_16x16x32_bf16(af[s], bf, fa1, 0, 0, 0);
      if (i == 2) fa2 = __builtin_amdgcn_mfma_f32_16x16x32_bf16(af[s], bf, fa2, 0, 0, 0);
      if (i == 3) fa3 = __builtin_amdgcn_mfma_f32_16x16x32_bf16(af[s], bf, fa3, 0, 0, 0);
    }
  }
#pragma unroll
  for (int i = 0; i < 4; ++i) {
    f32x4 fa = (i == 0) ? fa0 : (i == 1) ? fa1 : (i == 2) ? fa2 : fa3;
    int n = (w * 4 + i) * 16 + r16;
    float fb = fb1[n];
#pragma unroll
    for (int rr = 0; rr < 4; ++rr)
      h3s[(g * 4 + rr) * 260 + n] = fmaxf(fa[rr] + fb, 0.f);
  }
  __syncthreads();

  {
    int u = t >> 2, sub = t & 3;
    int cl = u >> 2, j = u & 3;
    const float4* hp = (const float4*)&h3s[cl * 260];
    const float4* wp = (const float4*)(fw2 + j * 256);
    float p = 0.f;
#pragma unroll
    for (int i = 0; i < 16; ++i) {
      int k4 = sub + 4 * i;
      float4 a = hp[k4], bb = wp[k4];
      p = fmaf(a.x, bb.x, p); p = fmaf(a.y, bb.y, p);
      p = fmaf(a.z, bb.z, p); p = fmaf(a.w, bb.w, p);
    }
    p += __shfl_xor(p, 1);
    p += __shfl_xor(p, 2);
    if (sub == 0) ls[cl][j] = p + fb2[j];
  }
  __syncthreads();

  if (t < 16) {
    float l0 = ls[t][0], l1 = ls[t][1], l2 = ls[t][2], l3 = ls[t][3];
    float m = fmaxf(fmaxf(l0, l1), fmaxf(l2, l3));
    float e0 = __expf(l0 - m), e1 = __expf(l1 - m),
          e2 = __expf(l2 - m), e3 = __expf(l3 - m);
    float inv = 1.f / (e0 + e1 + e2 + e3);
    int n = c0 + t;
    out[n] = e0 * inv;
    out[4096 + n] = e1 * inv;
    out[8192 + n] = e2 * inv;
  }
}

extern "C" void kernel_launch(void* const* d_in, const int* in_sizes, int n_in,
                              void* d_out, int out_size, void* d_ws, size_t ws_size,
                              hipStream_t stream) {
  const float* x   = (const float*)d_in[0];
  const float* w1  = (const float*)d_in[1];
  const float* b1  = (const float*)d_in[2];
  const float* w2  = (const float*)d_in[3];
  const float* b2  = (const float*)d_in[4];
  const float* fw1 = (const float*)d_in[5];
  const float* fb1 = (const float*)d_in[6];
  const float* fw2 = (const float*)d_in[7];
  const float* fb2 = (const float*)d_in[8];
  float* out = (float*)d_out;
  ushort* h2g = (ushort*)d_ws;   // 4096*288*2 = 2,359,296 B conv2 output (bf16)

  hipLaunchKernelGGL(conv_kernel, dim3(4096), dim3(256), 0, stream,
                     x, w1, b1, w2, b2, h2g);
  hipLaunchKernelGGL(fc_kernel, dim3(256), dim3(256), 0, stream,
                     fw1, fb1, fw2, fb2, h2g, out);
}

// Round 11
// 44.811 us; speedup vs baseline: 1.8173x; 1.4449x over previous
//
#include <hip/hip_runtime.h>

typedef float f32x4 __attribute__((ext_vector_type(4)));
typedef short s16x8 __attribute__((ext_vector_type(8)));

#define CB_PLANE 2704   // 52*52 ushorts
#define CB_ROW 52

// d_ws layout (ushort units)
#define WS_H2G  0                 // 4096*288
#define WS_FW1  1179648           // 256*288
#define WS_W1   1253376           // 16*192
#define WS_W2   1256448           // 32*256

// software f32->bf16 RNE (proven R3-R10)
__device__ __forceinline__ ushort f2bf(float f) {
  unsigned u = __float_as_uint(f);
  unsigned r = (u + 0x7fffu + ((u >> 16) & 1u)) >> 16;
  return (ushort)r;
}
__device__ __forceinline__ uint pk2(float a, float b) {
  return (uint)f2bf(a) | ((uint)f2bf(b) << 16);
}

// ---- prep: convert fw1 (73728), w1 (3072), w2 (8192) to bf16. 332*256 exact
__global__ void prep_kernel(const float* __restrict__ fw1,
                            const float* __restrict__ w1,
                            const float* __restrict__ w2,
                            ushort* __restrict__ ws) {
  int i = blockIdx.x * 256 + threadIdx.x;
  if (i < 73728)       ws[WS_FW1 + i] = f2bf(fw1[i]);
  else if (i < 76800)  ws[WS_W1 + i - 73728] = f2bf(w1[i - 73728]);
  else                 ws[WS_W2 + i - 76800] = f2bf(w2[i - 76800]);
}

// ---- conv1 epilogue: bias+relu, scatter into conv2 im2col (proven R8) ----
__device__ __forceinline__ void epi1(ushort* A2, f32x4 acc, int mt, int r16,
                                     int g, float b1v) {
#pragma unroll
  for (int rr = 0; rr < 4; ++rr) {
    int m = mt * 16 + g * 4 + rr;
    int oy = m / 12, ox = m - 12 * oy;
    if (oy < 11 && ox < 11) {
      float v = fmaxf(acc[rr] + b1v, 0.f);
      int py = (oy + 1) >> 2, k2y = (oy + 1) & 3;
      int px = (ox + 1) >> 2, k2x = (ox + 1) & 3;
      A2[(py * 3 + px) * 264 + r16 * 16 + k2y * 4 + k2x] = f2bf(v);
    }
  }
}

// ======== Kernel A: conv1 + conv2, 4 cells per block, double-buffered ======
__global__ __launch_bounds__(256, 4)
void conv_kernel(const float* __restrict__ x,
                 const ushort* __restrict__ w1b, const float* __restrict__ b1,
                 const ushort* __restrict__ w2b, const float* __restrict__ b2,
                 ushort* __restrict__ h2g)
{
  __shared__ __align__(16) ushort cb[2][3 * CB_PLANE];  // 32448 B, double buffer
  __shared__ __align__(16) ushort A2[16 * 264];         // 8448 B im2col

  const int t = threadIdx.x;
  const int w = t >> 6;
  const int r16 = t & 15;
  const int g = (t & 63) >> 4;
  const int cell0 = blockIdx.x * 4;

  // ---- staging descriptors (cell-invariant): 1728 float4 over 7 slots ----
  int goff[7], eoff[7];
#pragma unroll
  for (int i = 0; i < 7; ++i) {
    int q = i * 256 + t;
    int qq = (i < 6 || t < 192) ? q : 0;
    int c = qq / 576; int r2 = qq - c * 576;
    int y = r2 / 12;  int quad = r2 - y * 12;
    goff[i] = c * 36864 + y * 96 + quad;
    eoff[i] = c * CB_PLANE + (y + 2) * CB_ROW + 2 + quad * 4;
  }
  const float4* x4 = (const float4*)x;

  // ---- issue cell0 loads immediately ----
  float4 v[7];
  {
    int n = cell0, b = n >> 6, gg = n & 63;
    int base4 = b * 110592 + (gg >> 3) * 4608 + (gg & 7) * 12;
#pragma unroll
    for (int i = 0; i < 7; ++i)
      if (i < 6 || t < 192) v[i] = x4[base4 + goff[i]];
  }

  // ---- zero borders of BOTH buffers + A2 (disjoint from staged interiors) ----
  for (int i = t; i < 1200; i += 256) {
    int buf = i / 600, j = i - buf * 600;
    int pl = j / 200, r = j - pl * 200;
    int off;
    if (r < 52)        off = r;
    else if (r < 104)  off = 1300 + (r - 52);
    else if (r < 152)  off = (2 + (r - 104)) * 26;
    else               off = (2 + (r - 152)) * 26 + 25;
    ((uint*)cb[buf])[pl * 1352 + off] = 0u;
  }
  {
    uint4 z = make_uint4(0u, 0u, 0u, 0u);
    uint4* p2 = (uint4*)A2;
    for (int i = t; i < 528; i += 256) p2[i] = z;
  }

  // ---- conv1 B-fragments: single uint4 loads from pre-converted w1b ----
  s16x8 b1f[6];
#pragma unroll
  for (int s = 0; s < 6; ++s)
    b1f[s] = *(const s16x8*)&w1b[r16 * 192 + s * 32 + g * 8];
  const float b1v = b1[r16];
  const float b2v = b2[(w & 1) * 16 + r16];

  // ---- write cell0 pixels to cb[0] ----
#pragma unroll
  for (int i = 0; i < 7; ++i)
    if (i < 6 || t < 192) {
      uint* d = (uint*)&cb[0][eoff[i]];
      d[0] = pk2(v[i].x, v[i].y);
      d[1] = pk2(v[i].z, v[i].w);
    }

  // conv1 lane constants (proven R8-R10): wave w owns m-tiles {w, w+4}, wave 2 also 8
  const int mt0 = w, mt1 = w + 4;
  int m0 = mt0 * 16 + r16, m1 = mt1 * 16 + r16, m2_ = 128 + r16;
  const int rA0 = (m0 / 12) * (4 * CB_ROW) + 4 * (m0 % 12);
  const int rA1 = (m1 / 12) * (4 * CB_ROW) + 4 * (m1 % 12);
  const int rA2 = (m2_ / 12) * (4 * CB_ROW) + 4 * (m2_ % 12);

  __syncthreads();

  for (int cl = 0; cl < 4; ++cl) {
    // ---- issue next cell's loads (latency hidden under conv1) ----
    if (cl < 3) {
      int n = cell0 + cl + 1, b = n >> 6, gg = n & 63;
      int base4 = b * 110592 + (gg >> 3) * 4608 + (gg & 7) * 12;
#pragma unroll
      for (int i = 0; i < 7; ++i)
        if (i < 6 || t < 192) v[i] = x4[base4 + goff[i]];
    }

    // ---- conv1 MFMA on cb[cl&1] ----
    const ushort* cbc = cb[cl & 1];
    f32x4 a0 = (f32x4){0.f, 0.f, 0.f, 0.f};
    f32x4 a1 = (f32x4){0.f, 0.f, 0.f, 0.f};
    f32x4 a2 = (f32x4){0.f, 0.f, 0.f, 0.f};
#pragma unroll
    for (int s = 0; s < 6; ++s) {
      int sbase = (s >> 1) * CB_PLANE + ((s & 1) * 4 + g) * CB_ROW;
      s16x8 a;
      ((uint2*)&a)[0] = *(const uint2*)&cbc[sbase + rA0];
      ((uint2*)&a)[1] = *(const uint2*)&cbc[sbase + rA0 + 4];
      a0 = __builtin_amdgcn_mfma_f32_16x16x32_bf16(a, b1f[s], a0, 0, 0, 0);
      ((uint2*)&a)[0] = *(const uint2*)&cbc[sbase + rA1];
      ((uint2*)&a)[1] = *(const uint2*)&cbc[sbase + rA1 + 4];
      a1 = __builtin_amdgcn_mfma_f32_16x16x32_bf16(a, b1f[s], a1, 0, 0, 0);
      if (w == 2) {
        ((uint2*)&a)[0] = *(const uint2*)&cbc[sbase + rA2];
        ((uint2*)&a)[1] = *(const uint2*)&cbc[sbase + rA2 + 4];
        a2 = __builtin_amdgcn_mfma_f32_16x16x32_bf16(a, b1f[s], a2, 0, 0, 0);
      }
    }
    epi1(A2, a0, mt0, r16, g, b1v);
    epi1(A2, a1, mt1, r16, g, b1v);
    if (w == 2) epi1(A2, a2, 8, r16, g, b1v);

    __syncthreads();   // A2 complete; cb[(cl+1)&1] free (its readers passed)

    // ---- conv2 (waves 0,1) overlapped with staging writes (all waves) ----
    if (w < 2) {
      f32x4 c2acc = (f32x4){0.f, 0.f, 0.f, 0.f};
#pragma unroll
      for (int s2 = 0; s2 < 8; ++s2) {
        uint4 av = *(const uint4*)&A2[r16 * 264 + s2 * 32 + g * 8];
        s16x8 bf = *(const s16x8*)&w2b[(w * 16 + r16) * 256 + s2 * 32 + g * 8];
        c2acc = __builtin_amdgcn_mfma_f32_16x16x32_bf16(*(s16x8*)&av, bf, c2acc, 0, 0, 0);
      }
#pragma unroll
      for (int rr = 0; rr < 4; ++rr) {
        int p2 = g * 4 + rr;
        if (p2 < 9) {
          float vv = fmaxf(c2acc[rr] + b2v, 0.f);
          h2g[(cell0 + cl) * 288 + (w * 16 + r16) * 9 + p2] = f2bf(vv);
        }
      }
    }
    if (cl < 3) {
      ushort* dst = cb[(cl + 1) & 1];
#pragma unroll
      for (int i = 0; i < 7; ++i)
        if (i < 6 || t < 192) {
          uint* d = (uint*)&dst[eoff[i]];
          d[0] = pk2(v[i].x, v[i].y);
          d[1] = pk2(v[i].z, v[i].w);
        }
    }
    __syncthreads();   // conv2 reads of A2 + staging writes complete
  }
}

// ============ Kernel B: fc1(MFMA) + fc2 + softmax (fw1b pre-converted) =====
__global__ __launch_bounds__(256, 4)
void fc_kernel(const ushort* __restrict__ fw1b, const float* __restrict__ fb1,
               const float* __restrict__ fw2, const float* __restrict__ fb2,
               const ushort* __restrict__ h2g, float* __restrict__ out)
{
  __shared__ __align__(16) ushort h2s[16 * 296];
  __shared__ __align__(16) float h3s[16 * 260];
  __shared__ float ls[16][4];

  const int t = threadIdx.x;
  const int w = t >> 6;
  const int r16 = t & 15;
  const int g = (t & 63) >> 4;
  const int c0 = blockIdx.x * 16;

  const uint* src = (const uint*)(h2g + c0 * 288);
  for (int j = t; j < 2304; j += 256) {
    int r = j / 144, ci = j - r * 144;
    *(uint*)&h2s[r * 296 + 2 * ci] = src[j];
  }
  __syncthreads();

  s16x8 af[9];
#pragma unroll
  for (int s = 0; s < 9; ++s)
    af[s] = *(const s16x8*)&h2s[r16 * 296 + s * 32 + g * 8];

  f32x4 fa0 = (f32x4){0.f,0.f,0.f,0.f}, fa1 = fa0, fa2 = fa0, fa3 = fa0;
#pragma unroll
  for (int s = 0; s < 9; ++s) {
    const int ko = s * 32 + g * 8;
#pragma unroll
    for (int i = 0; i < 4; ++i) {
      s16x8 bf = *(const s16x8*)&fw1b[((w * 4 + i) * 16 + r16) * 288 + ko];
      if (i == 0) fa0 = __builtin_amdgcn_mfma_f32_16x16x32_bf16(af[s], bf, fa0, 0, 0, 0);
      if (i == 1) fa1 = __builtin_amdgcn_mfma_f32_16x16x32_bf16(af[s], bf, fa1, 0, 0, 0);
      if (i == 2) fa2 = __builtin_amdgcn_mfma_f32_16x16x32_bf16(af[s], bf, fa2, 0, 0, 0);
      if (i == 3) fa3 = __builtin_amdgcn_mfma_f32_16x16x32_bf16(af[s], bf, fa3, 0, 0, 0);
    }
  }
#pragma unroll
  for (int i = 0; i < 4; ++i) {
    f32x4 fa = (i == 0) ? fa0 : (i == 1) ? fa1 : (i == 2) ? fa2 : fa3;
    int n = (w * 4 + i) * 16 + r16;
    float fb = fb1[n];
#pragma unroll
    for (int rr = 0; rr < 4; ++rr)
      h3s[(g * 4 + rr) * 260 + n] = fmaxf(fa[rr] + fb, 0.f);
  }
  __syncthreads();

  {
    int u = t >> 2, sub = t & 3;
    int cl = u >> 2, j = u & 3;
    const float4* hp = (const float4*)&h3s[cl * 260];
    const float4* wp = (const float4*)(fw2 + j * 256);
    float p = 0.f;
#pragma unroll
    for (int i = 0; i < 16; ++i) {
      int k4 = sub + 4 * i;
      float4 a = hp[k4], bb = wp[k4];
      p = fmaf(a.x, bb.x, p); p = fmaf(a.y, bb.y, p);
      p = fmaf(a.z, bb.z, p); p = fmaf(a.w, bb.w, p);
    }
    p += __shfl_xor(p, 1);
    p += __shfl_xor(p, 2);
    if (sub == 0) ls[cl][j] = p + fb2[j];
  }
  __syncthreads();

  if (t < 16) {
    float l0 = ls[t][0], l1 = ls[t][1], l2 = ls[t][2], l3 = ls[t][3];
    float m = fmaxf(fmaxf(l0, l1), fmaxf(l2, l3));
    float e0 = __expf(l0 - m), e1 = __expf(l1 - m),
          e2 = __expf(l2 - m), e3 = __expf(l3 - m);
    float inv = 1.f / (e0 + e1 + e2 + e3);
    int n = c0 + t;
    out[n] = e0 * inv;
    out[4096 + n] = e1 * inv;
    out[8192 + n] = e2 * inv;
  }
}

extern "C" void kernel_launch(void* const* d_in, const int* in_sizes, int n_in,
                              void* d_out, int out_size, void* d_ws, size_t ws_size,
                              hipStream_t stream) {
  const float* x   = (const float*)d_in[0];
  const float* w1  = (const float*)d_in[1];
  const float* b1  = (const float*)d_in[2];
  const float* w2  = (const float*)d_in[3];
  const float* b2  = (const float*)d_in[4];
  const float* fw1 = (const float*)d_in[5];
  const float* fb1 = (const float*)d_in[6];
  const float* fw2 = (const float*)d_in[7];
  const float* fb2 = (const float*)d_in[8];
  float* out = (float*)d_out;
  ushort* ws = (ushort*)d_ws;   // h2g + bf16 weights, 2.53 MB total

  hipLaunchKernelGGL(prep_kernel, dim3(332), dim3(256), 0, stream,
                     fw1, w1, w2, ws);
  hipLaunchKernelGGL(conv_kernel, dim3(1024), dim3(256), 0, stream,
                     x, ws + WS_W1, b1, ws + WS_W2, b2, ws + WS_H2G);
  hipLaunchKernelGGL(fc_kernel, dim3(256), dim3(256), 0, stream,
                     ws + WS_FW1, fb1, fw2, fb2, ws + WS_H2G, out);
}